// Round 1
// baseline (325.965 us; speedup 1.0000x reference)
//
#include <hip/hip_runtime.h>

#define NB 16
#define HH 256
#define WW 256
#define HWSZ (HH * WW)
#define NPIX (NB * HWSZ)
#define BIGF 1e9f
#define IT 16

// ws layout (floats):
//   [0] ce_sum  [1] hard_sum  [2] hard_t_sum  [3] t_sum
//   [8..23]  S[b]   (sum of t1*res per sample)
//   [24..39] poscnt[b]
//   [64 .. 64+NB*HWSZ)            g2N  (row-dist^2 for dn = edt(neg): zeros at pos pixels)
//   [64+NB*HWSZ .. 64+2*NB*HWSZ)  g2P  (row-dist^2 for dp = edt(pos): zeros at neg pixels)
#define WS_G2N 64
#define WS_G2P (64 + NB * HWSZ)

// ---------------- Stage 1: per-pixel CE/dice terms + 1D row EDT ----------------
__global__ __launch_bounds__(256) void stage1_kernel(
    const float* __restrict__ inp, const int* __restrict__ tgt,
    float* __restrict__ ws) {
  const int row = blockIdx.x;          // b*HH + i
  const int b = row >> 8;
  const int i = row & 255;
  const int j = threadIdx.x;

  const size_t base = (size_t)(2 * b) * HWSZ + (size_t)i * WW + j;
  const float x0 = inp[base];
  const float x1 = inp[base + HWSZ];
  const int t = tgt[(size_t)row * WW + j];

  const bool pos = x1 > x0;    // argmax==1 (ties -> first index 0)
  const bool hard = x1 >= x0;  // probs1 >= 0.5

  // CE: lse - x_t
  const float mx = fmaxf(x0, x1);
  const float lse = mx + logf(expf(x0 - mx) + expf(x1 - mx));
  const float ce = lse - ((t == 1) ? x1 : x0);
  const float tf = (t == 1) ? 1.0f : 0.0f;
  const float hf = hard ? 1.0f : 0.0f;
  const float pf = pos ? 1.0f : 0.0f;

  // Pack this row's pos mask as 4 x 64-bit words (bit r of word q = pixel q*64+r)
  __shared__ unsigned long long wsh[4];
  const unsigned long long bal = __ballot(pos);
  if ((threadIdx.x & 63) == 0) wsh[threadIdx.x >> 6] = bal;
  __syncthreads();
  unsigned long long wp[4], wn[4];
#pragma unroll
  for (int q = 0; q < 4; ++q) { wp[q] = wsh[q]; wn[q] = ~wsh[q]; }

  // Nearest set bit <= j and >= j for both masks
  const int qj = j >> 6, rj = j & 63;
  const unsigned long long lowmask = (~0ull) >> (63 - rj);  // bits 0..rj
  const unsigned long long himask = (~0ull) << rj;          // bits rj..63

  int loP = -(1 << 20), loN = -(1 << 20);
#pragma unroll
  for (int q = 0; q < 4; ++q) {
    unsigned long long mp = wp[q], mn = wn[q];
    if (q == qj) { mp &= lowmask; mn &= lowmask; }
    else if (q > qj) { mp = 0ull; mn = 0ull; }
    if (mp) loP = (q << 6) + 63 - __builtin_clzll(mp);
    if (mn) loN = (q << 6) + 63 - __builtin_clzll(mn);
  }
  int hiP = (1 << 20), hiN = (1 << 20);
#pragma unroll
  for (int q = 3; q >= 0; --q) {
    unsigned long long mp = wp[q], mn = wn[q];
    if (q == qj) { mp &= himask; mn &= himask; }
    else if (q < qj) { mp = 0ull; mn = 0ull; }
    if (mp) hiP = (q << 6) + (int)__builtin_ctzll(mp);
    if (mn) hiN = (q << 6) + (int)__builtin_ctzll(mn);
  }
  const int dN = min(j - loP, hiP - j);  // dist to nearest pos pixel in row
  const int dP = min(j - loN, hiN - j);  // dist to nearest neg pixel in row
  const float gN = (dN > WW) ? BIGF : (float)dN;
  const float gP = (dP > WW) ? BIGF : (float)dP;
  ws[WS_G2N + (size_t)row * WW + j] = gN * gN;
  ws[WS_G2P + (size_t)row * WW + j] = gP * gP;

  // Block reductions: ce, hard, hard*t, t, pos-count
  float v0 = ce, v1 = hf, v2 = hf * tf, v3 = tf, v4 = pf;
#pragma unroll
  for (int off = 32; off > 0; off >>= 1) {
    v0 += __shfl_down(v0, off);
    v1 += __shfl_down(v1, off);
    v2 += __shfl_down(v2, off);
    v3 += __shfl_down(v3, off);
    v4 += __shfl_down(v4, off);
  }
  __shared__ float red[4][5];
  const int lane = threadIdx.x & 63, wid = threadIdx.x >> 6;
  if (lane == 0) {
    red[wid][0] = v0; red[wid][1] = v1; red[wid][2] = v2;
    red[wid][3] = v3; red[wid][4] = v4;
  }
  __syncthreads();
  if (threadIdx.x == 0) {
    float s0 = 0.f, s1 = 0.f, s2 = 0.f, s3 = 0.f, s4 = 0.f;
#pragma unroll
    for (int q = 0; q < 4; ++q) {
      s0 += red[q][0]; s1 += red[q][1]; s2 += red[q][2];
      s3 += red[q][3]; s4 += red[q][4];
    }
    atomicAdd(&ws[0], s0);
    atomicAdd(&ws[1], s1);
    atomicAdd(&ws[2], s2);
    atomicAdd(&ws[3], s3);
    atomicAdd(&ws[24 + b], s4);
  }
}

// ---------------- Stage 2: column pass of EDT + boundary accumulation ----------------
__global__ __launch_bounds__(256) void stage2_kernel(
    const float* __restrict__ inp, const int* __restrict__ tgt,
    float* __restrict__ ws) {
  const int b = blockIdx.x >> 4;              // 16 row-tiles per sample
  const int i0 = (blockIdx.x & 15) * IT;
  const int j = threadIdx.x;
  const float* g2N = ws + WS_G2N + (size_t)b * HWSZ;
  const float* g2P = ws + WS_G2P + (size_t)b * HWSZ;

  float mN[IT], mP[IT];
#pragma unroll
  for (int ii = 0; ii < IT; ++ii) { mN[ii] = 3.0e38f; mP[ii] = 3.0e38f; }

#pragma unroll 4
  for (int k = 0; k < HH; ++k) {
    const float gN = g2N[k * WW + j];
    const float gP = g2P[k * WW + j];
#pragma unroll
    for (int ii = 0; ii < IT; ++ii) {
      const int di = i0 + ii - k;             // wave-uniform
      const float dd = (float)(di * di);
      mN[ii] = fminf(mN[ii], gN + dd);
      mP[ii] = fminf(mP[ii], gP + dd);
    }
  }

  float local = 0.0f;
#pragma unroll
  for (int ii = 0; ii < IT; ++ii) {
    const int i = i0 + ii;
    const size_t base = (size_t)(2 * b) * HWSZ + (size_t)i * WW + j;
    const float x0 = inp[base];
    const float x1 = inp[base + HWSZ];
    const int t = tgt[(size_t)b * HWSZ + (size_t)i * WW + j];
    const bool pos = x1 > x0;
    const float dn = sqrtf(mN[ii]);
    const float dp = sqrtf(mP[ii]);
    // res = dn*neg - (dp-1)*pos
    const float res = pos ? (1.0f - dp) : dn;
    local += (t == 1) ? res : 0.0f;
  }

#pragma unroll
  for (int off = 32; off > 0; off >>= 1) local += __shfl_down(local, off);
  __shared__ float red[4];
  const int lane = threadIdx.x & 63, wid = threadIdx.x >> 6;
  if (lane == 0) red[wid] = local;
  __syncthreads();
  if (threadIdx.x == 0)
    atomicAdd(&ws[8 + b], red[0] + red[1] + red[2] + red[3]);
}

// ---------------- Stage 3: finalize scalar ----------------
__global__ void stage3_kernel(const float* __restrict__ ws, float* __restrict__ out) {
  const float ce = ws[0] * (1.0f / (float)NPIX);
  const float dice_loss =
      1.0f - (2.0f * ws[2] + 1.0f) / (ws[1] + ws[3] + 1.0f);
  float lb = 0.0f;
  for (int b = 0; b < NB; ++b)
    lb += (ws[24 + b] > 0.0f) ? ws[8 + b] * (1.0f / (float)HWSZ) : 0.0f;
  out[0] = ce + dice_loss + lb * lb;
}

extern "C" void kernel_launch(void* const* d_in, const int* in_sizes, int n_in,
                              void* d_out, int out_size, void* d_ws, size_t ws_size,
                              hipStream_t stream) {
  (void)in_sizes; (void)n_in; (void)out_size; (void)ws_size;
  const float* inp = (const float*)d_in[0];
  const int* tgt = (const int*)d_in[1];
  // d_in[2] starget, d_in[3] dice_co, d_in[4] boundary_co: unused by reference
  float* ws = (float*)d_ws;
  float* out = (float*)d_out;

  // ws is re-poisoned to 0xAA before every call: zero the accumulator header.
  hipMemsetAsync(d_ws, 0, 64 * sizeof(float), stream);
  stage1_kernel<<<NB * HH, 256, 0, stream>>>(inp, tgt, ws);
  stage2_kernel<<<NB * (HH / IT), 256, 0, stream>>>(inp, tgt, ws);
  stage3_kernel<<<1, 1, 0, stream>>>(ws, out);
}

// Round 2
// 86.900 us; speedup vs baseline: 3.7510x; 3.7510x over previous
//
#include <hip/hip_runtime.h>

#define NB 16
#define HH 256
#define WW 256
#define HWSZ (HH * WW)
#define NPIX (NB * HWSZ)
#define ROWS (NB * HH)  // 4096

// ws layout (4-byte units):
//   [0, NPIX)                 packed u16 pair per pixel: lo=dN (dist to nearest pos), hi=dP (to nearest neg)
//   [NPIX + v*ROWS + row]     P[v][row], v=0..4: per-row partials {ce, hard, hard*t, t, poscnt}
//   [NPIX + 5*ROWS + row]     part2[row]: per-row boundary sum
#define OFF_P NPIX
#define OFF_PART2 (NPIX + 5 * ROWS)

// ---------------- Stage 1: per-pixel CE/dice partials + 1D row EDT (bit tricks) ----------------
__global__ __launch_bounds__(256) void stage1_kernel(
    const float* __restrict__ inp, const int* __restrict__ tgt,
    unsigned int* __restrict__ wsu, float* __restrict__ wsf) {
  const int row = blockIdx.x;  // b*HH + i
  const int b = row >> 8;
  const int i = row & 255;
  const int j = threadIdx.x;

  const size_t base = (size_t)(2 * b) * HWSZ + (size_t)i * WW + j;
  const float x0 = inp[base];
  const float x1 = inp[base + HWSZ];
  const int t = tgt[(size_t)row * WW + j];

  const bool pos = x1 > x0;    // argmax==1 (ties -> class 0)
  const bool hard = x1 >= x0;  // probs1 >= 0.5

  // CE: lse - x_t
  const float mx = fmaxf(x0, x1);
  const float lse = mx + logf(expf(x0 - mx) + expf(x1 - mx));
  const float ce = lse - ((t == 1) ? x1 : x0);
  const float tf = (t == 1) ? 1.0f : 0.0f;
  const float hf = hard ? 1.0f : 0.0f;
  const float pf = pos ? 1.0f : 0.0f;

  // Row pos-mask as 4x64-bit ballots
  __shared__ unsigned long long wsh[4];
  const unsigned long long bal = __ballot(pos);
  if ((threadIdx.x & 63) == 0) wsh[threadIdx.x >> 6] = bal;
  __syncthreads();
  unsigned long long wp[4], wn[4];
#pragma unroll
  for (int q = 0; q < 4; ++q) { wp[q] = wsh[q]; wn[q] = ~wsh[q]; }

  const int qj = j >> 6, rj = j & 63;
  const unsigned long long lowmask = (~0ull) >> (63 - rj);
  const unsigned long long himask = (~0ull) << rj;

  int loP = -(1 << 20), loN = -(1 << 20);
#pragma unroll
  for (int q = 0; q < 4; ++q) {
    unsigned long long mp = wp[q], mn = wn[q];
    if (q == qj) { mp &= lowmask; mn &= lowmask; }
    else if (q > qj) { mp = 0ull; mn = 0ull; }
    if (mp) loP = (q << 6) + 63 - __builtin_clzll(mp);
    if (mn) loN = (q << 6) + 63 - __builtin_clzll(mn);
  }
  int hiP = (1 << 20), hiN = (1 << 20);
#pragma unroll
  for (int q = 3; q >= 0; --q) {
    unsigned long long mp = wp[q], mn = wn[q];
    if (q == qj) { mp &= himask; mn &= himask; }
    else if (q < qj) { mp = 0ull; mn = 0ull; }
    if (mp) hiP = (q << 6) + (int)__builtin_ctzll(mp);
    if (mn) hiN = (q << 6) + (int)__builtin_ctzll(mn);
  }
  const int dN = min(j - loP, hiP - j);  // dist to nearest pos pixel in row
  const int dP = min(j - loN, hiN - j);  // dist to nearest neg pixel in row
  const unsigned int dNc = (dN > 255) ? 0xFFFFu : (unsigned int)dN;
  const unsigned int dPc = (dP > 255) ? 0xFFFFu : (unsigned int)dP;
  wsu[(size_t)row * WW + j] = dNc | (dPc << 16);

  // Block reduction of 5 scalars -> per-row partials (NO global atomics)
  float v0 = ce, v1 = hf, v2 = hf * tf, v3 = tf, v4 = pf;
#pragma unroll
  for (int off = 32; off > 0; off >>= 1) {
    v0 += __shfl_down(v0, off);
    v1 += __shfl_down(v1, off);
    v2 += __shfl_down(v2, off);
    v3 += __shfl_down(v3, off);
    v4 += __shfl_down(v4, off);
  }
  __shared__ float red[4][5];
  const int lane = threadIdx.x & 63, wid = threadIdx.x >> 6;
  if (lane == 0) {
    red[wid][0] = v0; red[wid][1] = v1; red[wid][2] = v2;
    red[wid][3] = v3; red[wid][4] = v4;
  }
  __syncthreads();
  if (threadIdx.x == 0) {
    float s[5] = {0.f, 0.f, 0.f, 0.f, 0.f};
#pragma unroll
    for (int q = 0; q < 4; ++q) {
      s[0] += red[q][0]; s[1] += red[q][1]; s[2] += red[q][2];
      s[3] += red[q][3]; s[4] += red[q][4];
    }
#pragma unroll
    for (int v = 0; v < 5; ++v) wsf[OFF_P + v * ROWS + row] = s[v];
  }
}

// ---------------- Stage 2: windowed exact column EDT + boundary partial ----------------
__global__ __launch_bounds__(256) void stage2_kernel(
    const float* __restrict__ inp, const int* __restrict__ tgt,
    const unsigned int* __restrict__ wsu, float* __restrict__ wsf) {
  const int row = blockIdx.x;
  const int b = row >> 8;
  const int i = row & 255;
  const int j = threadIdx.x;
  const unsigned int* g = wsu + (size_t)b * HWSZ;

  // r = 0 candidate
  const unsigned int v0 = g[i * WW + j];
  const float a0 = (float)(v0 & 0xFFFFu);
  const float b0 = (float)(v0 >> 16);
  float mN = a0 * a0;  // running min for dn^2 (edt of neg mask: zeros at pos pixels)
  float mP = b0 * b0;  // running min for dp^2

  // Outward exact search: any skipped k has (i-k)^2 >= r^2 >= current min
  const int rmax = max(i, 255 - i);
  for (int r = 1; r <= rmax; ++r) {
    const float rr = (float)(r * r);
    if (!__ballot((rr < mN) || (rr < mP))) break;  // whole wave done
    if (i - r >= 0) {
      const unsigned int u = g[(i - r) * WW + j];
      const float a = (float)(u & 0xFFFFu);
      const float bb = (float)(u >> 16);
      mN = fminf(mN, a * a + rr);
      mP = fminf(mP, bb * bb + rr);
    }
    if (i + r < HH) {
      const unsigned int u = g[(i + r) * WW + j];
      const float a = (float)(u & 0xFFFFu);
      const float bb = (float)(u >> 16);
      mN = fminf(mN, a * a + rr);
      mP = fminf(mP, bb * bb + rr);
    }
  }

  const size_t base = (size_t)(2 * b) * HWSZ + (size_t)i * WW + j;
  const float x0 = inp[base];
  const float x1 = inp[base + HWSZ];
  const int t = tgt[(size_t)row * WW + j];
  const bool pos = x1 > x0;
  // res = dn*neg - (dp-1)*pos
  const float res = pos ? (1.0f - sqrtf(mP)) : sqrtf(mN);
  float local = (t == 1) ? res : 0.0f;

#pragma unroll
  for (int off = 32; off > 0; off >>= 1) local += __shfl_down(local, off);
  __shared__ float red[4];
  const int lane = threadIdx.x & 63, wid = threadIdx.x >> 6;
  if (lane == 0) red[wid] = local;
  __syncthreads();
  if (threadIdx.x == 0)
    wsf[OFF_PART2 + row] = red[0] + red[1] + red[2] + red[3];
}

// ---------------- Stage 3: reduce all partials + finalize scalar ----------------
__global__ __launch_bounds__(256) void stage3_kernel(
    const float* __restrict__ wsf, float* __restrict__ out) {
  const int t = threadIdx.x;
  const float* P = wsf + OFF_P;

  // Global sums over 4096 rows for v=0..3
  float s0 = 0.f, s1 = 0.f, s2 = 0.f, s3 = 0.f;
#pragma unroll
  for (int gi = 0; gi < 16; ++gi) {
    const int idx = t + (gi << 8);
    s0 += P[0 * ROWS + idx];
    s1 += P[1 * ROWS + idx];
    s2 += P[2 * ROWS + idx];
    s3 += P[3 * ROWS + idx];
  }
#pragma unroll
  for (int off = 32; off > 0; off >>= 1) {
    s0 += __shfl_down(s0, off);
    s1 += __shfl_down(s1, off);
    s2 += __shfl_down(s2, off);
    s3 += __shfl_down(s3, off);
  }
  __shared__ float red[4][4];
  const int lane = t & 63, wid = t >> 6;
  if (lane == 0) { red[wid][0] = s0; red[wid][1] = s1; red[wid][2] = s2; red[wid][3] = s3; }

  // Per-sample sums: thread t -> sample b=t>>4, slot m=t&15, each sums 16 rows
  const int b = t >> 4, m = t & 15;
  float pc = 0.f, sb = 0.f;
#pragma unroll
  for (int k = 0; k < 16; ++k) {
    const int idx = (b << 8) + m + (k << 4);
    pc += P[4 * ROWS + idx];
    sb += wsf[OFF_PART2 + idx];
  }
  pc += __shfl_xor(pc, 1); pc += __shfl_xor(pc, 2);
  pc += __shfl_xor(pc, 4); pc += __shfl_xor(pc, 8);
  sb += __shfl_xor(sb, 1); sb += __shfl_xor(sb, 2);
  sb += __shfl_xor(sb, 4); sb += __shfl_xor(sb, 8);
  __shared__ float pcL[16], sbL[16];
  if (m == 0) { pcL[b] = pc; sbL[b] = sb; }
  __syncthreads();

  if (t == 0) {
    const float ceS = red[0][0] + red[1][0] + red[2][0] + red[3][0];
    const float hS  = red[0][1] + red[1][1] + red[2][1] + red[3][1];
    const float htS = red[0][2] + red[1][2] + red[2][2] + red[3][2];
    const float tS  = red[0][3] + red[1][3] + red[2][3] + red[3][3];
    const float ce = ceS * (1.0f / (float)NPIX);
    const float dice_loss = 1.0f - (2.0f * htS + 1.0f) / (hS + tS + 1.0f);
    float lb = 0.0f;
    for (int bb = 0; bb < NB; ++bb)
      lb += (pcL[bb] > 0.0f) ? sbL[bb] * (1.0f / (float)HWSZ) : 0.0f;
    out[0] = ce + dice_loss + lb * lb;
  }
}

extern "C" void kernel_launch(void* const* d_in, const int* in_sizes, int n_in,
                              void* d_out, int out_size, void* d_ws, size_t ws_size,
                              hipStream_t stream) {
  (void)in_sizes; (void)n_in; (void)out_size; (void)ws_size;
  const float* inp = (const float*)d_in[0];
  const int* tgt = (const int*)d_in[1];
  // d_in[2] starget, d_in[3] dice_co, d_in[4] boundary_co: unused by reference
  unsigned int* wsu = (unsigned int*)d_ws;
  float* wsf = (float*)d_ws;
  float* out = (float*)d_out;

  // No atomics anywhere -> no memset needed; all partial slots are fully overwritten.
  stage1_kernel<<<ROWS, 256, 0, stream>>>(inp, tgt, wsu, wsf);
  stage2_kernel<<<ROWS, 256, 0, stream>>>(inp, tgt, wsu, wsf);
  stage3_kernel<<<1, 256, 0, stream>>>(wsf, out);
}

// Round 3
// 84.816 us; speedup vs baseline: 3.8432x; 1.0246x over previous
//
#include <hip/hip_runtime.h>

#define NB 16
#define HH 256
#define WW 256
#define HWSZ (HH * WW)
#define NPIX (NB * HWSZ)
#define ROWS (NB * HH)  // 4096

// ws layout (4-byte units):
//   [0, NPIX)                 packed u16 pair per pixel: lo=dN (dist to nearest pos), hi=dP (to nearest neg)
//   [NPIX + v*ROWS + row]     P[v][row], v=0..4: per-row partials {ce, hard, hard*t, t, poscnt}
//   [NPIX + 5*ROWS + row]     part2[row]: per-row boundary sum
#define OFF_P NPIX
#define OFF_PART2 (NPIX + 5 * ROWS)

#define LOG2E 1.44269504088896340736f
#define LN2 0.69314718055994530942f

// softplus(z) = log(1+e^z) = max(z,0) + ln2*log2(1+exp2(-|z|*log2e))
__device__ __forceinline__ float softplus_fast(float z) {
  const float u = __builtin_amdgcn_exp2f(-fabsf(z) * LOG2E);
  return fmaxf(z, 0.0f) + LN2 * __builtin_amdgcn_logf(1.0f + u);
}

// ---------------- Stage 1: per-pixel CE/dice partials + 1D row EDT (bit tricks) ----------------
__global__ __launch_bounds__(256) void stage1_kernel(
    const float* __restrict__ inp, const int* __restrict__ tgt,
    unsigned int* __restrict__ wsu, float* __restrict__ wsf) {
  const int row = blockIdx.x;  // b*HH + i
  const int b = row >> 8;
  const int i = row & 255;
  const int j = threadIdx.x;

  const size_t base = (size_t)(2 * b) * HWSZ + (size_t)i * WW + j;
  const float x0 = inp[base];
  const float x1 = inp[base + HWSZ];
  const int t = tgt[(size_t)row * WW + j];

  const bool pos = x1 > x0;    // argmax==1 (ties -> class 0)
  const bool hard = x1 >= x0;  // probs1 >= 0.5

  // CE via 2-class softplus (hardware exp2/log2; ~1e-5 abs err vs 0.345 budget)
  const float d = x1 - x0;
  const float ce = softplus_fast((t == 1) ? -d : d);

  // Row pos-mask as 4x64-bit ballots
  __shared__ unsigned long long wsh[4];
  const unsigned long long bal = __ballot(pos);
  if ((threadIdx.x & 63) == 0) wsh[threadIdx.x >> 6] = bal;
  __syncthreads();
  unsigned long long wp[4], wn[4];
#pragma unroll
  for (int q = 0; q < 4; ++q) { wp[q] = wsh[q]; wn[q] = ~wsh[q]; }

  const int qj = j >> 6, rj = j & 63;
  const unsigned long long lowmask = (~0ull) >> (63 - rj);
  const unsigned long long himask = (~0ull) << rj;

  int loP = -(1 << 20), loN = -(1 << 20);
#pragma unroll
  for (int q = 0; q < 4; ++q) {
    unsigned long long mp = wp[q], mn = wn[q];
    if (q == qj) { mp &= lowmask; mn &= lowmask; }
    else if (q > qj) { mp = 0ull; mn = 0ull; }
    if (mp) loP = (q << 6) + 63 - __builtin_clzll(mp);
    if (mn) loN = (q << 6) + 63 - __builtin_clzll(mn);
  }
  int hiP = (1 << 20), hiN = (1 << 20);
#pragma unroll
  for (int q = 3; q >= 0; --q) {
    unsigned long long mp = wp[q], mn = wn[q];
    if (q == qj) { mp &= himask; mn &= himask; }
    else if (q < qj) { mp = 0ull; mn = 0ull; }
    if (mp) hiP = (q << 6) + (int)__builtin_ctzll(mp);
    if (mn) hiN = (q << 6) + (int)__builtin_ctzll(mn);
  }
  const int dN = min(j - loP, hiP - j);  // dist to nearest pos pixel in row
  const int dP = min(j - loN, hiN - j);  // dist to nearest neg pixel in row
  const unsigned int dNc = (dN > 255) ? 0xFFFFu : (unsigned int)dN;
  const unsigned int dPc = (dP > 255) ? 0xFFFFu : (unsigned int)dP;
  wsu[(size_t)row * WW + j] = dNc | (dPc << 16);

  // Block reduction: ce (float) + packed counters (16-bit fields, sums<=256: no carry)
  const int tf = (t == 1) ? 1 : 0;
  float v0 = ce;
  int p1 = (hard ? 1 : 0) | ((hard && tf) ? 0x10000 : 0);  // h | ht<<16
  int p2 = tf | (pos ? 0x10000 : 0);                       // t | pf<<16
#pragma unroll
  for (int off = 32; off > 0; off >>= 1) {
    v0 += __shfl_down(v0, off);
    p1 += __shfl_down(p1, off);
    p2 += __shfl_down(p2, off);
  }
  __shared__ float redf[4];
  __shared__ int redi[4][2];
  const int lane = threadIdx.x & 63, wid = threadIdx.x >> 6;
  if (lane == 0) { redf[wid] = v0; redi[wid][0] = p1; redi[wid][1] = p2; }
  __syncthreads();
  if (threadIdx.x == 0) {
    float sce = 0.f;
    int s1 = 0, s2 = 0;
#pragma unroll
    for (int q = 0; q < 4; ++q) { sce += redf[q]; s1 += redi[q][0]; s2 += redi[q][1]; }
    wsf[OFF_P + 0 * ROWS + row] = sce;
    wsf[OFF_P + 1 * ROWS + row] = (float)(s1 & 0xFFFF);
    wsf[OFF_P + 2 * ROWS + row] = (float)(s1 >> 16);
    wsf[OFF_P + 3 * ROWS + row] = (float)(s2 & 0xFFFF);
    wsf[OFF_P + 4 * ROWS + row] = (float)(s2 >> 16);
  }
}

// ---------------- Stage 2: windowed exact column EDT + boundary partial ----------------
__global__ __launch_bounds__(256) void stage2_kernel(
    const int* __restrict__ tgt,
    const unsigned int* __restrict__ wsu, float* __restrict__ wsf) {
  const int row = blockIdx.x;
  const int b = row >> 8;
  const int i = row & 255;
  const int j = threadIdx.x;
  const unsigned int* g = wsu + (size_t)b * HWSZ;

  // r = 0 candidate; pos <=> dN == 0 (no inp re-read needed)
  const unsigned int v0 = g[i * WW + j];
  const bool pos = (v0 & 0xFFFFu) == 0u;
  const float a0 = (float)(v0 & 0xFFFFu);
  const float b0 = (float)(v0 >> 16);
  float mN = a0 * a0;  // running min for dn^2 (edt of neg mask: zeros at pos pixels)
  float mP = b0 * b0;  // running min for dp^2

  // Outward exact search: any skipped k has (i-k)^2 >= r^2 >= current min
  const int rmax = max(i, 255 - i);
  for (int r = 1; r <= rmax; ++r) {
    const float rr = (float)(r * r);
    if (!__ballot((rr < mN) || (rr < mP))) break;  // whole wave done
    if (i - r >= 0) {
      const unsigned int u = g[(i - r) * WW + j];
      const float a = (float)(u & 0xFFFFu);
      const float bb = (float)(u >> 16);
      mN = fminf(mN, a * a + rr);
      mP = fminf(mP, bb * bb + rr);
    }
    if (i + r < HH) {
      const unsigned int u = g[(i + r) * WW + j];
      const float a = (float)(u & 0xFFFFu);
      const float bb = (float)(u >> 16);
      mN = fminf(mN, a * a + rr);
      mP = fminf(mP, bb * bb + rr);
    }
  }

  const int t = tgt[(size_t)row * WW + j];
  // res = dn*neg - (dp-1)*pos
  const float res = pos ? (1.0f - sqrtf(mP)) : sqrtf(mN);
  float local = (t == 1) ? res : 0.0f;

#pragma unroll
  for (int off = 32; off > 0; off >>= 1) local += __shfl_down(local, off);
  __shared__ float red[4];
  const int lane = threadIdx.x & 63, wid = threadIdx.x >> 6;
  if (lane == 0) red[wid] = local;
  __syncthreads();
  if (threadIdx.x == 0)
    wsf[OFF_PART2 + row] = red[0] + red[1] + red[2] + red[3];
}

// ---------------- Stage 3: reduce all partials + finalize scalar ----------------
__global__ __launch_bounds__(256) void stage3_kernel(
    const float* __restrict__ wsf, float* __restrict__ out) {
  const int t = threadIdx.x;
  const float* P = wsf + OFF_P;

  // Global sums over 4096 rows for v=0..3
  float s0 = 0.f, s1 = 0.f, s2 = 0.f, s3 = 0.f;
#pragma unroll
  for (int gi = 0; gi < 16; ++gi) {
    const int idx = t + (gi << 8);
    s0 += P[0 * ROWS + idx];
    s1 += P[1 * ROWS + idx];
    s2 += P[2 * ROWS + idx];
    s3 += P[3 * ROWS + idx];
  }
#pragma unroll
  for (int off = 32; off > 0; off >>= 1) {
    s0 += __shfl_down(s0, off);
    s1 += __shfl_down(s1, off);
    s2 += __shfl_down(s2, off);
    s3 += __shfl_down(s3, off);
  }
  __shared__ float red[4][4];
  const int lane = t & 63, wid = t >> 6;
  if (lane == 0) { red[wid][0] = s0; red[wid][1] = s1; red[wid][2] = s2; red[wid][3] = s3; }

  // Per-sample sums: thread t -> sample b=t>>4, slot m=t&15, each sums 16 rows
  const int b = t >> 4, m = t & 15;
  float pc = 0.f, sb = 0.f;
#pragma unroll
  for (int k = 0; k < 16; ++k) {
    const int idx = (b << 8) + m + (k << 4);
    pc += P[4 * ROWS + idx];
    sb += wsf[OFF_PART2 + idx];
  }
  pc += __shfl_xor(pc, 1); pc += __shfl_xor(pc, 2);
  pc += __shfl_xor(pc, 4); pc += __shfl_xor(pc, 8);
  sb += __shfl_xor(sb, 1); sb += __shfl_xor(sb, 2);
  sb += __shfl_xor(sb, 4); sb += __shfl_xor(sb, 8);
  __shared__ float pcL[16], sbL[16];
  if (m == 0) { pcL[b] = pc; sbL[b] = sb; }
  __syncthreads();

  if (t == 0) {
    const float ceS = red[0][0] + red[1][0] + red[2][0] + red[3][0];
    const float hS  = red[0][1] + red[1][1] + red[2][1] + red[3][1];
    const float htS = red[0][2] + red[1][2] + red[2][2] + red[3][2];
    const float tS  = red[0][3] + red[1][3] + red[2][3] + red[3][3];
    const float ce = ceS * (1.0f / (float)NPIX);
    const float dice_loss = 1.0f - (2.0f * htS + 1.0f) / (hS + tS + 1.0f);
    float lb = 0.0f;
    for (int bb = 0; bb < NB; ++bb)
      lb += (pcL[bb] > 0.0f) ? sbL[bb] * (1.0f / (float)HWSZ) : 0.0f;
    out[0] = ce + dice_loss + lb * lb;
  }
}

extern "C" void kernel_launch(void* const* d_in, const int* in_sizes, int n_in,
                              void* d_out, int out_size, void* d_ws, size_t ws_size,
                              hipStream_t stream) {
  (void)in_sizes; (void)n_in; (void)out_size; (void)ws_size;
  const float* inp = (const float*)d_in[0];
  const int* tgt = (const int*)d_in[1];
  // d_in[2] starget, d_in[3] dice_co, d_in[4] boundary_co: unused by reference
  unsigned int* wsu = (unsigned int*)d_ws;
  float* wsf = (float*)d_ws;
  float* out = (float*)d_out;

  // No atomics anywhere -> no memset needed; all partial slots are fully overwritten.
  stage1_kernel<<<ROWS, 256, 0, stream>>>(inp, tgt, wsu, wsf);
  stage2_kernel<<<ROWS, 256, 0, stream>>>(tgt, wsu, wsf);
  stage3_kernel<<<1, 256, 0, stream>>>(wsf, out);
}